// Round 16
// baseline (461.125 us; speedup 1.0000x reference)
//
#include <hip/hip_runtime.h>
#include <hip/hip_bf16.h>
#include <math.h>

#define TPB 256

typedef __attribute__((ext_vector_type(8))) short bf16x8;
typedef __attribute__((ext_vector_type(4))) float f32x4;
typedef __attribute__((ext_vector_type(4))) unsigned u32x4;

__device__ __forceinline__ unsigned cvt_bf(float f) {
    unsigned u = __float_as_uint(f);
    u += 0x7fffu + ((u >> 16) & 1u);
    return u >> 16;
}
__device__ __forceinline__ unsigned pack2f(float a, float b) {
    __hip_bfloat162 h = __float22bfloat162_rn(float2{a, b});
    unsigned u;
    __builtin_memcpy(&u, &h, 4);
    return u;
}

__device__ __forceinline__ void gload16(const void* g, void* l) {
    __builtin_amdgcn_global_load_lds(
        (const __attribute__((address_space(1))) void*)g,
        (__attribute__((address_space(3))) void*)l, 16, 0, 0);
}

// ---------------- degree / CSR build ----------------

__global__ void k_hist(const int* __restrict__ dst, int* __restrict__ cnt, int E) {
    int e = blockIdx.x * TPB + threadIdx.x;
    if (e < E) atomicAdd(&cnt[dst[e]], 1);
}

__global__ __launch_bounds__(256)
void k_scan1(const int* __restrict__ cnt, int* __restrict__ incl,
             int* __restrict__ bsum, int n) {
    __shared__ int sh[256];
    const int t = threadIdx.x;
    const int i = blockIdx.x * 256 + t;
    int v = (i < n) ? cnt[i] : 0;
    sh[t] = v;
    __syncthreads();
#pragma unroll
    for (int d = 1; d < 256; d <<= 1) {
        int u = (t >= d) ? sh[t - d] : 0;
        __syncthreads();
        sh[t] += u;
        __syncthreads();
    }
    if (i < n) incl[i] = sh[t];
    if (t == 255) bsum[blockIdx.x] = sh[255];
}

__global__ __launch_bounds__(256)
void k_scan2(int* __restrict__ bsum, int* __restrict__ boff,
             int* __restrict__ row_start, int n, int nb) {
    __shared__ int sh[256];
    const int t = threadIdx.x;
    int v = (t < nb) ? bsum[t] : 0;
    sh[t] = v;
    __syncthreads();
#pragma unroll
    for (int d = 1; d < 256; d <<= 1) {
        int u = (t >= d) ? sh[t - d] : 0;
        __syncthreads();
        sh[t] += u;
        __syncthreads();
    }
    if (t < nb) boff[t] = sh[t] - v;
    if (t == nb - 1) row_start[n] = sh[t];
}

__global__ void k_scan3(const int* __restrict__ cnt, const int* __restrict__ incl,
                        const int* __restrict__ boff, int* __restrict__ row_start,
                        int* __restrict__ cursor, float* __restrict__ dis, int n) {
    int i = blockIdx.x * TPB + threadIdx.x;
    if (i >= n) return;
    int c = cnt[i];
    int ex = boff[i >> 8] + incl[i] - c;
    row_start[i] = ex;
    cursor[i] = ex;
    dis[i] = rsqrtf((float)c + 1.0f);
}

__global__ void k_fill_csr(const int* __restrict__ src, const int* __restrict__ dst,
                           const float* __restrict__ dis, int* __restrict__ cursor,
                           int* __restrict__ csr_src, float* __restrict__ csr_nrm, int E) {
    int e = blockIdx.x * TPB + threadIdx.x;
    if (e >= E) return;
    int s = src[e], d = dst[e];
    int pos = atomicAdd(&cursor[d], 1);
    csr_src[pos] = s;
    csr_nrm[pos] = dis[s] * dis[d];
}

// ---------------- fused prep ----------------

__global__ __launch_bounds__(256)
void k_prep(const float* __restrict__ x, unsigned short* __restrict__ xbf, int n8, int nbA,
            const float* __restrict__ W1, unsigned short* __restrict__ w1t,
            const float* __restrict__ W2, unsigned short* __restrict__ w2bf,
            const float* __restrict__ lpW1, unsigned short* __restrict__ lpw1t,
            const float* __restrict__ b2, const float* __restrict__ lpb1,
            float* __restrict__ bias_big) {
    int b = blockIdx.x;
    if (b < nbA) {
        int i = b * TPB + threadIdx.x;
        if (i >= n8) return;
        float4 f0 = *(const float4*)(x + (size_t)i * 8);
        float4 f1 = *(const float4*)(x + (size_t)i * 8 + 4);
        uint4 o;
        o.x = pack2f(f0.x, f0.y); o.y = pack2f(f0.z, f0.w);
        o.z = pack2f(f1.x, f1.y); o.w = pack2f(f1.z, f1.w);
        *(uint4*)(xbf + (size_t)i * 8) = o;
        return;
    }
    b -= nbA;
    if (b < 1024) {
        int id = b * TPB + threadIdx.x;
        int nn = id >> 9, k = id & 511;
        w1t[id] = (unsigned short)cvt_bf(W1[(size_t)k * 512 + nn]);
        return;
    }
    b -= 1024;
    if (b < 128) {
        int i = b * TPB + threadIdx.x;
        float4 f0 = *(const float4*)(W2 + (size_t)i * 8);
        float4 f1 = *(const float4*)(W2 + (size_t)i * 8 + 4);
        uint4 o;
        o.x = pack2f(f0.x, f0.y); o.y = pack2f(f0.z, f0.w);
        o.z = pack2f(f1.x, f1.y); o.w = pack2f(f1.z, f1.w);
        *(uint4*)(w2bf + (size_t)i * 8) = o;
        return;
    }
    b -= 128;
    if (b < 2048) {
        int id = b * TPB + threadIdx.x;
        int j = id >> 9, k = id & 511;
        float v = (j < 512) ? lpW1[(size_t)k * 512 + j]
                            : lpW1[(size_t)(512 + k) * 512 + (j - 512)];
        lpw1t[id] = (unsigned short)cvt_bf(v);
        return;
    }
    b -= 2048;
    {
        const int j = b * 4 + (threadIdx.x >> 6);
        if (j >= 1024) return;
        const int lane = threadIdx.x & 63;
        const int col = (j < 512) ? j : (j - 512);
        const int ro = (j < 512) ? 0 : 512;
        float s = 0.f;
#pragma unroll
        for (int it = 0; it < 8; ++it) {
            int k = lane + it * 64;
            s = fmaf(b2[k], lpW1[(size_t)(ro + k) * 512 + col], s);
        }
        s += __shfl_xor(s, 1, 64);
        s += __shfl_xor(s, 2, 64);
        s += __shfl_xor(s, 4, 64);
        s += __shfl_xor(s, 8, 64);
        s += __shfl_xor(s, 16, 64);
        s += __shfl_xor(s, 32, 64);
        if (lane == 0) bias_big[j] = s + ((j < 512) ? lpb1[j] : 0.f);
    }
}

// ---------------- CSR gather aggregation: 2-stage pipelined (idx ahead of gather) ----------------

__device__ __forceinline__ void fma8(float* acc, uint4 u, float r) {
    acc[0] = fmaf(__uint_as_float(u.x << 16), r, acc[0]);
    acc[1] = fmaf(__uint_as_float(u.x & 0xffff0000u), r, acc[1]);
    acc[2] = fmaf(__uint_as_float(u.y << 16), r, acc[2]);
    acc[3] = fmaf(__uint_as_float(u.y & 0xffff0000u), r, acc[3]);
    acc[4] = fmaf(__uint_as_float(u.z << 16), r, acc[4]);
    acc[5] = fmaf(__uint_as_float(u.z & 0xffff0000u), r, acc[5]);
    acc[6] = fmaf(__uint_as_float(u.w << 16), r, acc[6]);
    acc[7] = fmaf(__uint_as_float(u.w & 0xffff0000u), r, acc[7]);
}

__global__ __launch_bounds__(256)
void k_agg_bf(const unsigned short* __restrict__ xin, const int* __restrict__ row_start,
              const int* __restrict__ csr_src, const float* __restrict__ csr_nrm,
              const float* __restrict__ dis, unsigned short* __restrict__ out, int n) {
    const int v = (blockIdx.x * TPB + threadIdx.x) >> 6;
    if (v >= n) return;
    const int lane = threadIdx.x & 63;
    const uint4* base = (const uint4*)xin;

    float d = dis[v]; float d2 = d * d;
    float acc[8];
    {
        uint4 u = base[(size_t)v * 64 + lane];
        acc[0] = d2 * __uint_as_float(u.x << 16);
        acc[1] = d2 * __uint_as_float(u.x & 0xffff0000u);
        acc[2] = d2 * __uint_as_float(u.y << 16);
        acc[3] = d2 * __uint_as_float(u.y & 0xffff0000u);
        acc[4] = d2 * __uint_as_float(u.z << 16);
        acc[5] = d2 * __uint_as_float(u.z & 0xffff0000u);
        acc[6] = d2 * __uint_as_float(u.w << 16);
        acc[7] = d2 * __uint_as_float(u.w & 0xffff0000u);
    }
    const int beg = row_start[v], end = row_start[v + 1];
    int j = beg;
    if (end - beg >= 8) {
        int   i1[4]; float r0_[4], r1_[4];
        uint4 u0[4];
#pragma unroll
        for (int q = 0; q < 4; ++q) { int i0 = csr_src[j + q]; r0_[q] = csr_nrm[j + q];
                                      u0[q] = base[(size_t)i0 * 64 + lane]; }
#pragma unroll
        for (int q = 0; q < 4; ++q) { i1[q] = csr_src[j + 4 + q]; r1_[q] = csr_nrm[j + 4 + q]; }
        j += 8;
        while (j + 3 < end) {
            int i2[4]; float r2_[4];
#pragma unroll
            for (int q = 0; q < 4; ++q) { i2[q] = csr_src[j + q]; r2_[q] = csr_nrm[j + q]; }
            uint4 u1[4];
#pragma unroll
            for (int q = 0; q < 4; ++q) u1[q] = base[(size_t)i1[q] * 64 + lane];
#pragma unroll
            for (int q = 0; q < 4; ++q) fma8(acc, u0[q], r0_[q]);
#pragma unroll
            for (int q = 0; q < 4; ++q) { u0[q] = u1[q]; r0_[q] = r1_[q];
                                          i1[q] = i2[q]; r1_[q] = r2_[q]; }
            j += 4;
        }
        uint4 u1[4];
#pragma unroll
        for (int q = 0; q < 4; ++q) u1[q] = base[(size_t)i1[q] * 64 + lane];
#pragma unroll
        for (int q = 0; q < 4; ++q) fma8(acc, u0[q], r0_[q]);
#pragma unroll
        for (int q = 0; q < 4; ++q) fma8(acc, u1[q], r1_[q]);
    }
    for (; j < end; ++j) {
        uint4 u = base[(size_t)csr_src[j] * 64 + lane];
        fma8(acc, u, csr_nrm[j]);
    }
    u32x4 o;
    o.x = pack2f(acc[0], acc[1]); o.y = pack2f(acc[2], acc[3]);
    o.z = pack2f(acc[4], acc[5]); o.w = pack2f(acc[6], acc[7]);
    __builtin_nontemporal_store(o, (u32x4*)out + (size_t)v * 64 + lane);
}

// ---------------- bf16 MFMA GEMM (R12 structure, nt C-stores) ----------------

__global__ __launch_bounds__(256)
void k_gemm_bf(const unsigned short* __restrict__ A, const unsigned short* __restrict__ Bt,
               const float* __restrict__ bias, unsigned short* __restrict__ C,
               int M, int K, int N, int do_relu, int nbx) {
    const int lin = blockIdx.x;
    const int xcd = lin & 7, seq = lin >> 3;
    const int rowt = xcd + 8 * (seq / nbx);
    const int colt = seq % nbx;
    const int m0 = rowt * 128;
    if (m0 >= M) return;
    const int n0 = colt * 128;

    __shared__ __align__(16) char smem[16384];
    char* Asl = smem;
    char* Bsl = smem + 8192;
    const int t = threadIdx.x;
    const int wid = t >> 6, l = t & 63;
    const int wr = (wid >> 1) * 64, wc = (wid & 1) * 64;
    const int lrow = l & 15, g = l >> 4;

    const int srow = (l >> 2);
    const int cb_src = ((l & 3) * 16) ^ ((srow & 3) << 4);
    const int r0 = wid * 32 + srow, r1 = r0 + 16;
    const size_t rowA0 = (size_t)min(m0 + r0, M - 1) * K * 2;
    const size_t rowA1 = (size_t)min(m0 + r1, M - 1) * K * 2;
    const size_t rowB0 = (size_t)(n0 + r0) * K * 2;
    const size_t rowB1 = (size_t)(n0 + r1) * K * 2;
    const char* Ab = (const char*)A;
    const char* Bb = (const char*)Bt;
    char* ldsA0 = Asl + (wid * 32) * 64;
    char* ldsA1 = ldsA0 + 16 * 64;
    char* ldsB0 = Bsl + (wid * 32) * 64;
    char* ldsB1 = ldsB0 + 16 * 64;
    const int rd_off = (g * 16) ^ ((lrow & 3) << 4);

    f32x4 acc[4][4] = {};
    for (int k0 = 0; k0 < K; k0 += 32) {
        const size_t koff = (size_t)k0 * 2 + cb_src;
        gload16(Ab + rowA0 + koff, ldsA0);
        gload16(Ab + rowA1 + koff, ldsA1);
        gload16(Bb + rowB0 + koff, ldsB0);
        gload16(Bb + rowB1 + koff, ldsB1);
        __syncthreads();
        bf16x8 af[4], bfr[4];
#pragma unroll
        for (int i = 0; i < 4; ++i)
            af[i] = *(const bf16x8*)(Asl + (wr + i * 16 + lrow) * 64 + rd_off);
#pragma unroll
        for (int j = 0; j < 4; ++j)
            bfr[j] = *(const bf16x8*)(Bsl + (wc + j * 16 + lrow) * 64 + rd_off);
#pragma unroll
        for (int i = 0; i < 4; ++i)
#pragma unroll
            for (int j = 0; j < 4; ++j)
                acc[i][j] = __builtin_amdgcn_mfma_f32_16x16x32_bf16(af[i], bfr[j], acc[i][j], 0, 0, 0);
        __syncthreads();
    }

    float bv[4];
#pragma unroll
    for (int j = 0; j < 4; ++j) bv[j] = bias[n0 + wc + j * 16 + lrow];
    float* lws = (float*)(smem + wid * 4096);
    const int rrow = l >> 2, rcol = (l & 3) * 16;
#pragma unroll
    for (int i = 0; i < 4; ++i) {
#pragma unroll
        for (int e = 0; e < 4; ++e)
#pragma unroll
            for (int j = 0; j < 4; ++j) {
                float vv = acc[i][j][e] + bv[j];
                if (do_relu) vv = fmaxf(vv, 0.f);
                lws[(g * 4 + e) * 64 + j * 16 + lrow] = vv;
            }
        asm volatile("s_waitcnt lgkmcnt(0)" ::: "memory");
        __builtin_amdgcn_sched_barrier(0);
        const int grow = m0 + wr + i * 16 + rrow;
        float4 f0 = *(const float4*)&lws[rrow * 64 + rcol];
        float4 f1 = *(const float4*)&lws[rrow * 64 + rcol + 4];
        float4 f2 = *(const float4*)&lws[rrow * 64 + rcol + 8];
        float4 f3 = *(const float4*)&lws[rrow * 64 + rcol + 12];
        if (grow < M) {
            u32x4 o0, o1;
            o0.x = pack2f(f0.x, f0.y); o0.y = pack2f(f0.z, f0.w);
            o0.z = pack2f(f1.x, f1.y); o0.w = pack2f(f1.z, f1.w);
            o1.x = pack2f(f2.x, f2.y); o1.y = pack2f(f2.z, f2.w);
            o1.z = pack2f(f3.x, f3.y); o1.w = pack2f(f3.z, f3.w);
            __builtin_nontemporal_store(o0, (u32x4*)(C + (size_t)grow * N + n0 + wc + rcol));
            __builtin_nontemporal_store(o1, (u32x4*)(C + (size_t)grow * N + n0 + wc + rcol + 8));
        }
        asm volatile("s_waitcnt lgkmcnt(0)" ::: "memory");
        __builtin_amdgcn_sched_barrier(0);
    }
}

// ---------------- pair pass ----------------

__global__ __launch_bounds__(256)
void k_pair(const unsigned short* __restrict__ uv, const int* __restrict__ pair, int P,
            const float* __restrict__ w2, const float* __restrict__ lpb2,
            float* __restrict__ out) {
    const int idx = (blockIdx.x * TPB + threadIdx.x) >> 6;
    if (idx >= P) return;
    const int lane = threadIdx.x & 63;
    const int p0n = pair[idx], p1n = pair[P + idx];
    const uint4 a = *(const uint4*)(uv + (size_t)p0n * 1024 + lane * 8);
    const uint4 b = *(const uint4*)(uv + (size_t)p1n * 1024 + 512 + lane * 8);
    const float4 w0 = *(const float4*)(w2 + lane * 8);
    const float4 w1 = *(const float4*)(w2 + lane * 8 + 4);
    const unsigned ua[4] = {a.x, a.y, a.z, a.w};
    const unsigned ub[4] = {b.x, b.y, b.z, b.w};
    const float wv[8] = {w0.x, w0.y, w0.z, w0.w, w1.x, w1.y, w1.z, w1.w};
    float s = 0.f;
#pragma unroll
    for (int q = 0; q < 4; ++q) {
        float h0 = __uint_as_float(ua[q] << 16) + __uint_as_float(ub[q] << 16);
        float h1 = __uint_as_float(ua[q] & 0xffff0000u) + __uint_as_float(ub[q] & 0xffff0000u);
        s = fmaf(fmaxf(h0, 0.f), wv[2 * q], s);
        s = fmaf(fmaxf(h1, 0.f), wv[2 * q + 1], s);
    }
    s += __shfl_xor(s, 1, 64);
    s += __shfl_xor(s, 2, 64);
    s += __shfl_xor(s, 4, 64);
    s += __shfl_xor(s, 8, 64);
    s += __shfl_xor(s, 16, 64);
    s += __shfl_xor(s, 32, 64);
    if (lane == 0) out[idx] = 1.0f / (1.0f + expf(-(s + lpb2[0])));
}

// ---------------- launcher ----------------

extern "C" void kernel_launch(void* const* d_in, const int* in_sizes, int n_in,
                              void* d_out, int out_size, void* d_ws, size_t ws_size,
                              hipStream_t stream) {
    const float* x    = (const float*)d_in[0];
    const int*   ei   = (const int*)d_in[1];
    const int*   ep   = (const int*)d_in[2];
    const float* W1   = (const float*)d_in[3];
    const float* b1   = (const float*)d_in[4];
    const float* W2   = (const float*)d_in[5];
    const float* b2   = (const float*)d_in[6];
    const float* lpW1 = (const float*)d_in[7];
    const float* lpb1 = (const float*)d_in[8];
    const float* lpW2 = (const float*)d_in[9];
    const float* lpb2 = (const float*)d_in[10];

    const int n = in_sizes[0] / 512;
    const int E = in_sizes[1] / 2;
    const int P = in_sizes[2] / 2;
    const int* src = ei;
    const int* dst = ei + E;

    char* w = (char*)d_ws;
    size_t off = 0;
    auto alloc = [&](size_t bytes) {
        void* p = w + off;
        off = (off + bytes + 255) & ~(size_t)255;
        return p;
    };
    int*   cnt       = (int*)alloc((size_t)n * 4);
    int*   incl      = (int*)alloc((size_t)n * 4);
    int*   bsum      = (int*)alloc((size_t)256 * 4);
    int*   boff      = (int*)alloc((size_t)256 * 4);
    int*   row_start = (int*)alloc((size_t)(n + 1) * 4);
    int*   cursor    = (int*)alloc((size_t)n * 4);
    int*   csr_src   = (int*)alloc((size_t)E * 4);
    float* csr_nrm   = (float*)alloc((size_t)E * 4);
    float* dis       = (float*)alloc((size_t)n * 4);
    unsigned short* w1t    = (unsigned short*)alloc((size_t)512 * 512 * 2);
    unsigned short* w2bf   = (unsigned short*)alloc((size_t)512 * 512 * 2);
    unsigned short* lpw1t  = (unsigned short*)alloc((size_t)1024 * 512 * 2);
    unsigned short* wfT    = (unsigned short*)alloc((size_t)1024 * 512 * 2);
    float* bias_big  = (float*)alloc((size_t)1024 * 4);
    float* zerob     = (float*)alloc((size_t)1024 * 4);
    unsigned short* bufA = (unsigned short*)alloc((size_t)n * 512 * 2);
    unsigned short* bufB = (unsigned short*)alloc((size_t)n * 512 * 2);
    unsigned short* uv   = (unsigned short*)alloc((size_t)n * 1024 * 2);

    dim3 blk(TPB);
    const int nb_n = (n + TPB - 1) / TPB;
    const int nb_E = (E + TPB - 1) / TPB;
    const int nb_scan = (n + 255) / 256;

    // CSR build + norms
    (void)hipMemsetAsync(cnt, 0, (size_t)n * 4, stream);
    (void)hipMemsetAsync(zerob, 0, (size_t)1024 * 4, stream);
    k_hist<<<nb_E, blk, 0, stream>>>(dst, cnt, E);
    k_scan1<<<nb_scan, 256, 0, stream>>>(cnt, incl, bsum, n);
    k_scan2<<<1, 256, 0, stream>>>(bsum, boff, row_start, n, nb_scan);
    k_scan3<<<nb_n, blk, 0, stream>>>(cnt, incl, boff, row_start, cursor, dis, n);
    k_fill_csr<<<nb_E, blk, 0, stream>>>(src, dst, dis, cursor, csr_src, csr_nrm, E);

    // fused prep
    const int n8  = n * 64;
    const int nbA = (n8 + TPB - 1) / TPB;
    const int prep_blocks = nbA + 1024 + 128 + 2048 + 256;
    k_prep<<<prep_blocks, blk, 0, stream>>>(x, bufA, n8, nbA, W1, w1t, W2, w2bf,
                                            lpW1, lpw1t, b2, lpb1, bias_big);

    const int gy  = (n + 127) / 128;
    const int gy8 = ((gy + 7) / 8) * 8;
    const int agg_blocks = (n * 64 + TPB - 1) / TPB;

    // WfusedT[j][i] = sum_k lpW1ext[k][j] * W2[i][k]
    k_gemm_bf<<<4 * 8, blk, 0, stream>>>(lpw1t, w2bf, zerob, wfT, 1024, 512, 512, 0, 4);

    // layer 1: y1 = A_hat x ; z1 = relu(y1 @ W1 + b1)
    k_agg_bf<<<agg_blocks, blk, 0, stream>>>(bufA, row_start, csr_src, csr_nrm, dis, bufB, n);
    k_gemm_bf<<<4 * gy8, blk, 0, stream>>>(bufB, w1t, b1, bufA, n, 512, 512, 1, 4);
    // layer 2 folded: y2 = A_hat z1 ; uv = y2 @ Wfused + bias_big
    k_agg_bf<<<agg_blocks, blk, 0, stream>>>(bufA, row_start, csr_src, csr_nrm, dis, bufB, n);
    k_gemm_bf<<<8 * gy8, blk, 0, stream>>>(bufB, wfT, bias_big, uv, n, 512, 1024, 0, 8);

    // pair pass (fused relu + dot + sigmoid)
    k_pair<<<(P * 64 + TPB - 1) / TPB, blk, 0, stream>>>(uv, ep, P, lpW2, lpb2, (float*)d_out);
}

// Round 17
// 428.060 us; speedup vs baseline: 1.0772x; 1.0772x over previous
//
#include <hip/hip_runtime.h>
#include <hip/hip_bf16.h>
#include <math.h>

#define TPB 256

typedef __attribute__((ext_vector_type(8))) short bf16x8;
typedef __attribute__((ext_vector_type(4))) float f32x4;

__device__ __forceinline__ unsigned cvt_bf(float f) {
    unsigned u = __float_as_uint(f);
    u += 0x7fffu + ((u >> 16) & 1u);
    return u >> 16;
}
__device__ __forceinline__ unsigned pack2f(float a, float b) {
    __hip_bfloat162 h = __float22bfloat162_rn(float2{a, b});
    unsigned u;
    __builtin_memcpy(&u, &h, 4);
    return u;
}

__device__ __forceinline__ void gload16(const void* g, void* l) {
    __builtin_amdgcn_global_load_lds(
        (const __attribute__((address_space(1))) void*)g,
        (__attribute__((address_space(3))) void*)l, 16, 0, 0);
}

// ---------------- degree / CSR build ----------------

__global__ void k_hist(const int* __restrict__ dst, int* __restrict__ cnt, int E) {
    int e = blockIdx.x * TPB + threadIdx.x;
    if (e < E) atomicAdd(&cnt[dst[e]], 1);
}

__global__ __launch_bounds__(256)
void k_scan1(const int* __restrict__ cnt, int* __restrict__ incl,
             int* __restrict__ bsum, int n) {
    __shared__ int sh[256];
    const int t = threadIdx.x;
    const int i = blockIdx.x * 256 + t;
    int v = (i < n) ? cnt[i] : 0;
    sh[t] = v;
    __syncthreads();
#pragma unroll
    for (int d = 1; d < 256; d <<= 1) {
        int u = (t >= d) ? sh[t - d] : 0;
        __syncthreads();
        sh[t] += u;
        __syncthreads();
    }
    if (i < n) incl[i] = sh[t];
    if (t == 255) bsum[blockIdx.x] = sh[255];
}

__global__ __launch_bounds__(256)
void k_scan2(int* __restrict__ bsum, int* __restrict__ boff,
             int* __restrict__ row_start, int n, int nb) {
    __shared__ int sh[256];
    const int t = threadIdx.x;
    int v = (t < nb) ? bsum[t] : 0;
    sh[t] = v;
    __syncthreads();
#pragma unroll
    for (int d = 1; d < 256; d <<= 1) {
        int u = (t >= d) ? sh[t - d] : 0;
        __syncthreads();
        sh[t] += u;
        __syncthreads();
    }
    if (t < nb) boff[t] = sh[t] - v;
    if (t == nb - 1) row_start[n] = sh[t];
}

__global__ void k_scan3(const int* __restrict__ cnt, const int* __restrict__ incl,
                        const int* __restrict__ boff, int* __restrict__ row_start,
                        int* __restrict__ cursor, float* __restrict__ dis, int n) {
    int i = blockIdx.x * TPB + threadIdx.x;
    if (i >= n) return;
    int c = cnt[i];
    int ex = boff[i >> 8] + incl[i] - c;
    row_start[i] = ex;
    cursor[i] = ex;
    dis[i] = rsqrtf((float)c + 1.0f);
}

__global__ void k_fill_csr(const int* __restrict__ src, const int* __restrict__ dst,
                           const float* __restrict__ dis, int* __restrict__ cursor,
                           int* __restrict__ csr_src, float* __restrict__ csr_nrm, int E) {
    int e = blockIdx.x * TPB + threadIdx.x;
    if (e >= E) return;
    int s = src[e], d = dst[e];
    int pos = atomicAdd(&cursor[d], 1);
    csr_src[pos] = s;
    csr_nrm[pos] = dis[s] * dis[d];
}

// ---------------- fused prep ----------------

__global__ __launch_bounds__(256)
void k_prep(const float* __restrict__ x, unsigned short* __restrict__ xbf, int n8, int nbA,
            const float* __restrict__ W1, unsigned short* __restrict__ w1t,
            const float* __restrict__ W2, unsigned short* __restrict__ w2bf,
            const float* __restrict__ lpW1, unsigned short* __restrict__ lpw1t,
            const float* __restrict__ b2, const float* __restrict__ lpb1,
            float* __restrict__ bias_big) {
    int b = blockIdx.x;
    if (b < nbA) {
        int i = b * TPB + threadIdx.x;
        if (i >= n8) return;
        float4 f0 = *(const float4*)(x + (size_t)i * 8);
        float4 f1 = *(const float4*)(x + (size_t)i * 8 + 4);
        uint4 o;
        o.x = pack2f(f0.x, f0.y); o.y = pack2f(f0.z, f0.w);
        o.z = pack2f(f1.x, f1.y); o.w = pack2f(f1.z, f1.w);
        *(uint4*)(xbf + (size_t)i * 8) = o;
        return;
    }
    b -= nbA;
    if (b < 1024) {
        int id = b * TPB + threadIdx.x;
        int nn = id >> 9, k = id & 511;
        w1t[id] = (unsigned short)cvt_bf(W1[(size_t)k * 512 + nn]);
        return;
    }
    b -= 1024;
    if (b < 128) {
        int i = b * TPB + threadIdx.x;
        float4 f0 = *(const float4*)(W2 + (size_t)i * 8);
        float4 f1 = *(const float4*)(W2 + (size_t)i * 8 + 4);
        uint4 o;
        o.x = pack2f(f0.x, f0.y); o.y = pack2f(f0.z, f0.w);
        o.z = pack2f(f1.x, f1.y); o.w = pack2f(f1.z, f1.w);
        *(uint4*)(w2bf + (size_t)i * 8) = o;
        return;
    }
    b -= 128;
    if (b < 2048) {
        int id = b * TPB + threadIdx.x;
        int j = id >> 9, k = id & 511;
        float v = (j < 512) ? lpW1[(size_t)k * 512 + j]
                            : lpW1[(size_t)(512 + k) * 512 + (j - 512)];
        lpw1t[id] = (unsigned short)cvt_bf(v);
        return;
    }
    b -= 2048;
    {
        const int j = b * 4 + (threadIdx.x >> 6);
        if (j >= 1024) return;
        const int lane = threadIdx.x & 63;
        const int col = (j < 512) ? j : (j - 512);
        const int ro = (j < 512) ? 0 : 512;
        float s = 0.f;
#pragma unroll
        for (int it = 0; it < 8; ++it) {
            int k = lane + it * 64;
            s = fmaf(b2[k], lpW1[(size_t)(ro + k) * 512 + col], s);
        }
        s += __shfl_xor(s, 1, 64);
        s += __shfl_xor(s, 2, 64);
        s += __shfl_xor(s, 4, 64);
        s += __shfl_xor(s, 8, 64);
        s += __shfl_xor(s, 16, 64);
        s += __shfl_xor(s, 32, 64);
        if (lane == 0) bias_big[j] = s + ((j < 512) ? lpb1[j] : 0.f);
    }
}

// ---------------- CSR gather aggregation: 2-stage pipelined (idx ahead of gather) ----------------

__device__ __forceinline__ void fma8(float* acc, uint4 u, float r) {
    acc[0] = fmaf(__uint_as_float(u.x << 16), r, acc[0]);
    acc[1] = fmaf(__uint_as_float(u.x & 0xffff0000u), r, acc[1]);
    acc[2] = fmaf(__uint_as_float(u.y << 16), r, acc[2]);
    acc[3] = fmaf(__uint_as_float(u.y & 0xffff0000u), r, acc[3]);
    acc[4] = fmaf(__uint_as_float(u.z << 16), r, acc[4]);
    acc[5] = fmaf(__uint_as_float(u.z & 0xffff0000u), r, acc[5]);
    acc[6] = fmaf(__uint_as_float(u.w << 16), r, acc[6]);
    acc[7] = fmaf(__uint_as_float(u.w & 0xffff0000u), r, acc[7]);
}

__global__ __launch_bounds__(256)
void k_agg_bf(const unsigned short* __restrict__ xin, const int* __restrict__ row_start,
              const int* __restrict__ csr_src, const float* __restrict__ csr_nrm,
              const float* __restrict__ dis, unsigned short* __restrict__ out, int n) {
    const int v = (blockIdx.x * TPB + threadIdx.x) >> 6;
    if (v >= n) return;
    const int lane = threadIdx.x & 63;
    const uint4* base = (const uint4*)xin;

    float d = dis[v]; float d2 = d * d;
    float acc[8];
    {
        uint4 u = base[(size_t)v * 64 + lane];
        acc[0] = d2 * __uint_as_float(u.x << 16);
        acc[1] = d2 * __uint_as_float(u.x & 0xffff0000u);
        acc[2] = d2 * __uint_as_float(u.y << 16);
        acc[3] = d2 * __uint_as_float(u.y & 0xffff0000u);
        acc[4] = d2 * __uint_as_float(u.z << 16);
        acc[5] = d2 * __uint_as_float(u.z & 0xffff0000u);
        acc[6] = d2 * __uint_as_float(u.w << 16);
        acc[7] = d2 * __uint_as_float(u.w & 0xffff0000u);
    }
    const int beg = row_start[v], end = row_start[v + 1];
    int j = beg;
    if (end - beg >= 8) {
        int   i1[4]; float r0_[4], r1_[4];
        uint4 u0[4];
#pragma unroll
        for (int q = 0; q < 4; ++q) { int i0 = csr_src[j + q]; r0_[q] = csr_nrm[j + q];
                                      u0[q] = base[(size_t)i0 * 64 + lane]; }
#pragma unroll
        for (int q = 0; q < 4; ++q) { i1[q] = csr_src[j + 4 + q]; r1_[q] = csr_nrm[j + 4 + q]; }
        j += 8;
        while (j + 3 < end) {
            int i2[4]; float r2_[4];
#pragma unroll
            for (int q = 0; q < 4; ++q) { i2[q] = csr_src[j + q]; r2_[q] = csr_nrm[j + q]; }
            uint4 u1[4];
#pragma unroll
            for (int q = 0; q < 4; ++q) u1[q] = base[(size_t)i1[q] * 64 + lane];
#pragma unroll
            for (int q = 0; q < 4; ++q) fma8(acc, u0[q], r0_[q]);
#pragma unroll
            for (int q = 0; q < 4; ++q) { u0[q] = u1[q]; r0_[q] = r1_[q];
                                          i1[q] = i2[q]; r1_[q] = r2_[q]; }
            j += 4;
        }
        uint4 u1[4];
#pragma unroll
        for (int q = 0; q < 4; ++q) u1[q] = base[(size_t)i1[q] * 64 + lane];
#pragma unroll
        for (int q = 0; q < 4; ++q) fma8(acc, u0[q], r0_[q]);
#pragma unroll
        for (int q = 0; q < 4; ++q) fma8(acc, u1[q], r1_[q]);
    }
    for (; j < end; ++j) {
        uint4 u = base[(size_t)csr_src[j] * 64 + lane];
        fma8(acc, u, csr_nrm[j]);
    }
    uint4 o;
    o.x = pack2f(acc[0], acc[1]); o.y = pack2f(acc[2], acc[3]);
    o.z = pack2f(acc[4], acc[5]); o.w = pack2f(acc[6], acc[7]);
    ((uint4*)out)[(size_t)v * 64 + lane] = o;
}

// ---------------- bf16 MFMA GEMM (R12/R14 structure, plain stores) ----------------

__global__ __launch_bounds__(256)
void k_gemm_bf(const unsigned short* __restrict__ A, const unsigned short* __restrict__ Bt,
               const float* __restrict__ bias, unsigned short* __restrict__ C,
               int M, int K, int N, int do_relu, int nbx) {
    const int lin = blockIdx.x;
    const int xcd = lin & 7, seq = lin >> 3;
    const int rowt = xcd + 8 * (seq / nbx);
    const int colt = seq % nbx;
    const int m0 = rowt * 128;
    if (m0 >= M) return;
    const int n0 = colt * 128;

    __shared__ __align__(16) char smem[16384];
    char* Asl = smem;
    char* Bsl = smem + 8192;
    const int t = threadIdx.x;
    const int wid = t >> 6, l = t & 63;
    const int wr = (wid >> 1) * 64, wc = (wid & 1) * 64;
    const int lrow = l & 15, g = l >> 4;

    const int srow = (l >> 2);
    const int cb_src = ((l & 3) * 16) ^ ((srow & 3) << 4);
    const int r0 = wid * 32 + srow, r1 = r0 + 16;
    const size_t rowA0 = (size_t)min(m0 + r0, M - 1) * K * 2;
    const size_t rowA1 = (size_t)min(m0 + r1, M - 1) * K * 2;
    const size_t rowB0 = (size_t)(n0 + r0) * K * 2;
    const size_t rowB1 = (size_t)(n0 + r1) * K * 2;
    const char* Ab = (const char*)A;
    const char* Bb = (const char*)Bt;
    char* ldsA0 = Asl + (wid * 32) * 64;
    char* ldsA1 = ldsA0 + 16 * 64;
    char* ldsB0 = Bsl + (wid * 32) * 64;
    char* ldsB1 = ldsB0 + 16 * 64;
    const int rd_off = (g * 16) ^ ((lrow & 3) << 4);

    f32x4 acc[4][4] = {};
    for (int k0 = 0; k0 < K; k0 += 32) {
        const size_t koff = (size_t)k0 * 2 + cb_src;
        gload16(Ab + rowA0 + koff, ldsA0);
        gload16(Ab + rowA1 + koff, ldsA1);
        gload16(Bb + rowB0 + koff, ldsB0);
        gload16(Bb + rowB1 + koff, ldsB1);
        __syncthreads();
        bf16x8 af[4], bfr[4];
#pragma unroll
        for (int i = 0; i < 4; ++i)
            af[i] = *(const bf16x8*)(Asl + (wr + i * 16 + lrow) * 64 + rd_off);
#pragma unroll
        for (int j = 0; j < 4; ++j)
            bfr[j] = *(const bf16x8*)(Bsl + (wc + j * 16 + lrow) * 64 + rd_off);
#pragma unroll
        for (int i = 0; i < 4; ++i)
#pragma unroll
            for (int j = 0; j < 4; ++j)
                acc[i][j] = __builtin_amdgcn_mfma_f32_16x16x32_bf16(af[i], bfr[j], acc[i][j], 0, 0, 0);
        __syncthreads();
    }

    float bv[4];
#pragma unroll
    for (int j = 0; j < 4; ++j) bv[j] = bias[n0 + wc + j * 16 + lrow];
    float* lws = (float*)(smem + wid * 4096);
    const int rrow = l >> 2, rcol = (l & 3) * 16;
#pragma unroll
    for (int i = 0; i < 4; ++i) {
#pragma unroll
        for (int e = 0; e < 4; ++e)
#pragma unroll
            for (int j = 0; j < 4; ++j) {
                float vv = acc[i][j][e] + bv[j];
                if (do_relu) vv = fmaxf(vv, 0.f);
                lws[(g * 4 + e) * 64 + j * 16 + lrow] = vv;
            }
        asm volatile("s_waitcnt lgkmcnt(0)" ::: "memory");
        __builtin_amdgcn_sched_barrier(0);
        const int grow = m0 + wr + i * 16 + rrow;
        float4 f0 = *(const float4*)&lws[rrow * 64 + rcol];
        float4 f1 = *(const float4*)&lws[rrow * 64 + rcol + 4];
        float4 f2 = *(const float4*)&lws[rrow * 64 + rcol + 8];
        float4 f3 = *(const float4*)&lws[rrow * 64 + rcol + 12];
        if (grow < M) {
            uint4 o0, o1;
            o0.x = pack2f(f0.x, f0.y); o0.y = pack2f(f0.z, f0.w);
            o0.z = pack2f(f1.x, f1.y); o0.w = pack2f(f1.z, f1.w);
            o1.x = pack2f(f2.x, f2.y); o1.y = pack2f(f2.z, f2.w);
            o1.z = pack2f(f3.x, f3.y); o1.w = pack2f(f3.z, f3.w);
            *(uint4*)(C + (size_t)grow * N + n0 + wc + rcol)     = o0;
            *(uint4*)(C + (size_t)grow * N + n0 + wc + rcol + 8) = o1;
        }
        asm volatile("s_waitcnt lgkmcnt(0)" ::: "memory");
        __builtin_amdgcn_sched_barrier(0);
    }
}

// ---------------- pair pass ----------------

__global__ __launch_bounds__(256)
void k_pair(const unsigned short* __restrict__ uv, const int* __restrict__ pair, int P,
            const float* __restrict__ w2, const float* __restrict__ lpb2,
            float* __restrict__ out) {
    const int idx = (blockIdx.x * TPB + threadIdx.x) >> 6;
    if (idx >= P) return;
    const int lane = threadIdx.x & 63;
    const int p0n = pair[idx], p1n = pair[P + idx];
    const uint4 a = *(const uint4*)(uv + (size_t)p0n * 1024 + lane * 8);
    const uint4 b = *(const uint4*)(uv + (size_t)p1n * 1024 + 512 + lane * 8);
    const float4 w0 = *(const float4*)(w2 + lane * 8);
    const float4 w1 = *(const float4*)(w2 + lane * 8 + 4);
    const unsigned ua[4] = {a.x, a.y, a.z, a.w};
    const unsigned ub[4] = {b.x, b.y, b.z, b.w};
    const float wv[8] = {w0.x, w0.y, w0.z, w0.w, w1.x, w1.y, w1.z, w1.w};
    float s = 0.f;
#pragma unroll
    for (int q = 0; q < 4; ++q) {
        float h0 = __uint_as_float(ua[q] << 16) + __uint_as_float(ub[q] << 16);
        float h1 = __uint_as_float(ua[q] & 0xffff0000u) + __uint_as_float(ub[q] & 0xffff0000u);
        s = fmaf(fmaxf(h0, 0.f), wv[2 * q], s);
        s = fmaf(fmaxf(h1, 0.f), wv[2 * q + 1], s);
    }
    s += __shfl_xor(s, 1, 64);
    s += __shfl_xor(s, 2, 64);
    s += __shfl_xor(s, 4, 64);
    s += __shfl_xor(s, 8, 64);
    s += __shfl_xor(s, 16, 64);
    s += __shfl_xor(s, 32, 64);
    if (lane == 0) out[idx] = 1.0f / (1.0f + expf(-(s + lpb2[0])));
}

// ---------------- launcher ----------------

extern "C" void kernel_launch(void* const* d_in, const int* in_sizes, int n_in,
                              void* d_out, int out_size, void* d_ws, size_t ws_size,
                              hipStream_t stream) {
    const float* x    = (const float*)d_in[0];
    const int*   ei   = (const int*)d_in[1];
    const int*   ep   = (const int*)d_in[2];
    const float* W1   = (const float*)d_in[3];
    const float* b1   = (const float*)d_in[4];
    const float* W2   = (const float*)d_in[5];
    const float* b2   = (const float*)d_in[6];
    const float* lpW1 = (const float*)d_in[7];
    const float* lpb1 = (const float*)d_in[8];
    const float* lpW2 = (const float*)d_in[9];
    const float* lpb2 = (const float*)d_in[10];

    const int n = in_sizes[0] / 512;
    const int E = in_sizes[1] / 2;
    const int P = in_sizes[2] / 2;
    const int* src = ei;
    const int* dst = ei + E;

    char* w = (char*)d_ws;
    size_t off = 0;
    auto alloc = [&](size_t bytes) {
        void* p = w + off;
        off = (off + bytes + 255) & ~(size_t)255;
        return p;
    };
    int*   cnt       = (int*)alloc((size_t)n * 4);
    int*   incl      = (int*)alloc((size_t)n * 4);
    int*   bsum      = (int*)alloc((size_t)256 * 4);
    int*   boff      = (int*)alloc((size_t)256 * 4);
    int*   row_start = (int*)alloc((size_t)(n + 1) * 4);
    int*   cursor    = (int*)alloc((size_t)n * 4);
    int*   csr_src   = (int*)alloc((size_t)E * 4);
    float* csr_nrm   = (float*)alloc((size_t)E * 4);
    float* dis       = (float*)alloc((size_t)n * 4);
    unsigned short* w1t    = (unsigned short*)alloc((size_t)512 * 512 * 2);
    unsigned short* w2bf   = (unsigned short*)alloc((size_t)512 * 512 * 2);
    unsigned short* lpw1t  = (unsigned short*)alloc((size_t)1024 * 512 * 2);
    unsigned short* wfT    = (unsigned short*)alloc((size_t)1024 * 512 * 2);
    float* bias_big  = (float*)alloc((size_t)1024 * 4);
    float* zerob     = (float*)alloc((size_t)1024 * 4);
    unsigned short* bufA = (unsigned short*)alloc((size_t)n * 512 * 2);
    unsigned short* bufB = (unsigned short*)alloc((size_t)n * 512 * 2);
    unsigned short* uv   = (unsigned short*)alloc((size_t)n * 1024 * 2);

    dim3 blk(TPB);
    const int nb_n = (n + TPB - 1) / TPB;
    const int nb_E = (E + TPB - 1) / TPB;
    const int nb_scan = (n + 255) / 256;

    // CSR build + norms
    (void)hipMemsetAsync(cnt, 0, (size_t)n * 4, stream);
    (void)hipMemsetAsync(zerob, 0, (size_t)1024 * 4, stream);
    k_hist<<<nb_E, blk, 0, stream>>>(dst, cnt, E);
    k_scan1<<<nb_scan, 256, 0, stream>>>(cnt, incl, bsum, n);
    k_scan2<<<1, 256, 0, stream>>>(bsum, boff, row_start, n, nb_scan);
    k_scan3<<<nb_n, blk, 0, stream>>>(cnt, incl, boff, row_start, cursor, dis, n);
    k_fill_csr<<<nb_E, blk, 0, stream>>>(src, dst, dis, cursor, csr_src, csr_nrm, E);

    // fused prep
    const int n8  = n * 64;
    const int nbA = (n8 + TPB - 1) / TPB;
    const int prep_blocks = nbA + 1024 + 128 + 2048 + 256;
    k_prep<<<prep_blocks, blk, 0, stream>>>(x, bufA, n8, nbA, W1, w1t, W2, w2bf,
                                            lpW1, lpw1t, b2, lpb1, bias_big);

    const int gy  = (n + 127) / 128;
    const int gy8 = ((gy + 7) / 8) * 8;
    const int agg_blocks = (n * 64 + TPB - 1) / TPB;

    // WfusedT[j][i] = sum_k lpW1ext[k][j] * W2[i][k]
    k_gemm_bf<<<4 * 8, blk, 0, stream>>>(lpw1t, w2bf, zerob, wfT, 1024, 512, 512, 0, 4);

    // layer 1: y1 = A_hat x ; z1 = relu(y1 @ W1 + b1)
    k_agg_bf<<<agg_blocks, blk, 0, stream>>>(bufA, row_start, csr_src, csr_nrm, dis, bufB, n);
    k_gemm_bf<<<4 * gy8, blk, 0, stream>>>(bufB, w1t, b1, bufA, n, 512, 512, 1, 4);
    // layer 2 folded: y2 = A_hat z1 ; uv = y2 @ Wfused + bias_big
    k_agg_bf<<<agg_blocks, blk, 0, stream>>>(bufA, row_start, csr_src, csr_nrm, dis, bufB, n);
    k_gemm_bf<<<8 * gy8, blk, 0, stream>>>(bufB, wfT, bias_big, uv, n, 512, 1024, 0, 8);

    // pair pass (fused relu + dot + sigmoid)
    k_pair<<<(P * 64 + TPB - 1) / TPB, blk, 0, stream>>>(uv, ep, P, lpW2, lpb2, (float*)d_out);
}